// Round 3
// baseline (748.624 us; speedup 1.0000x reference)
//
#include <hip/hip_runtime.h>

#define TT 4096      // tokens
#define DM 1024      // d_model
#define DF 4096      // d_ff
#define NE 8         // experts
#define NSLOT 8192   // exactly 2*TT slots; M-overreach spills into adjacent ws (masked)

typedef short bf16x8 __attribute__((ext_vector_type(8)));
typedef float f32x4  __attribute__((ext_vector_type(4)));

// ---------- ws layout (bytes), total 218,234,880 (round-2 size, known OK) ----------
#define CNT_OFF    0
#define OFFS_OFF   256
#define POS_OFF    512
#define METAI_OFF  4096                       // int[TT]
#define METAG_OFF  (METAI_OFF + 4*TT)         // float[TT]
#define TSLOT_OFF  (METAG_OFF + 4*TT)         // int[TT]  (s0 | s1<<16)
#define XG_OFF     131072                     // ushort[NSLOT*DM]   (dead after gemm1)
#define W1T_OFF    (XG_OFF + 2*NSLOT*DM)      // ushort[NE*DF*DM] bf16 [e][f][k] (dead after gemm1)
#define H_OFF      (W1T_OFF + 2*NE*DM*DF)     // ushort[NSLOT*DF]
#define W2T_OFF    (H_OFF + 2*NSLOT*DF)       // ushort[NE*DM*DF] bf16 [e][d][k]
#define Y_OFF      XG_OFF                     // float[2][NSLOT*DM] aliases Xg+W1t

// fp32 pair -> packed bf16x2 (RNE)
__device__ __forceinline__ unsigned pkbf(float a, float b) {
    unsigned ua = __float_as_uint(a), ub = __float_as_uint(b);
    ua += 0x7fffu + ((ua >> 16) & 1u);
    ub += 0x7fffu + ((ub >> 16) & 1u);
    return __builtin_amdgcn_perm(ub, ua, 0x07060302u);
}

// async global->LDS, 16B per lane; LDS dest linear (wave-uniform base + lane*16)
__device__ __forceinline__ void gll16(const void* g, void* l) {
    __builtin_amdgcn_global_load_lds(
        (const __attribute__((address_space(1))) void*)g,
        (__attribute__((address_space(3))) void*)l, 16, 0, 0);
}

// ---- BK=32 LDS tile layout (256 rows x 32 k bf16 = 16KB per operand) ----
// Row pair packed per 128B line: byte(row,k) = (row>>1)*128 + phys*16 + (k&7)*2,
// phys = (((row&1)<<2)|(k>>3)) ^ ((row>>1)&7).  Full-wave b128 reads are
// bank-uniform (each of 8 lines hit on all 8 chunks exactly once) -> conflict-free.
// Staged via linear-dest gll16 with inverse-swizzled global source (rule #21).
__device__ __forceinline__ void stage32(const ushort* __restrict__ A, int ar0, int as,
                                        const ushort* __restrict__ B, int br0, int bs,
                                        int k0, char* buf, int tid)
{
#pragma unroll
    for (int i = 0; i < 2; i++) {                 // A: chunks 0..1023
        int c = i * 512 + tid;
        int line = c >> 3, lg = (c & 7) ^ (line & 7);
        int row = line * 2 + (lg >> 2), kb = (lg & 3) * 8;
        gll16(A + (size_t)(ar0 + row) * as + k0 + kb, buf + c * 16);
    }
#pragma unroll
    for (int i = 0; i < 2; i++) {                 // B: chunks 0..1023
        int c = i * 512 + tid;
        int line = c >> 3, lg = (c & 7) ^ (line & 7);
        int row = line * 2 + (lg >> 2), kb = (lg & 3) * 8;
        gll16(B + (size_t)(br0 + row) * bs + k0 + kb, buf + 16384 + c * 16);
    }
}

__device__ __forceinline__ const bf16x8* fragp(const char* base, int row, int q) {
    int line = row >> 1;
    int c = ((((row & 1) << 2) | q) ^ (line & 7));
    return (const bf16x8*)(base + line * 128 + c * 16);
}

// ---------------- init ----------------
__global__ void init_kernel(int* __restrict__ cnt)
{
    if (threadIdx.x < NE) cnt[threadIdx.x] = 0;
}

// ---------------- Router ----------------
__global__ __launch_bounds__(256)
void router_kernel(const float* __restrict__ x, const float* __restrict__ Wr,
                   const float* __restrict__ br,
                   int* __restrict__ cnt, int* __restrict__ meta_i,
                   float* __restrict__ meta_g)
{
    const int t    = (blockIdx.x * blockDim.x + threadIdx.x) >> 6;
    const int lane = threadIdx.x & 63;
    if (t >= TT) return;
    const float* xr = x + (size_t)t * DM;

    float acc[NE];
#pragma unroll
    for (int e = 0; e < NE; e++) acc[e] = 0.f;
    for (int i = 0; i < DM / 64; i++) {
        int d = lane + (i << 6);
        float xv = xr[d];
        const float4* wr = (const float4*)(Wr + (size_t)d * NE);
        float4 w0 = wr[0], w1 = wr[1];
        acc[0] += xv * w0.x; acc[1] += xv * w0.y;
        acc[2] += xv * w0.z; acc[3] += xv * w0.w;
        acc[4] += xv * w1.x; acc[5] += xv * w1.y;
        acc[6] += xv * w1.z; acc[7] += xv * w1.w;
    }
#pragma unroll
    for (int e = 0; e < NE; e++)
#pragma unroll
        for (int off = 32; off > 0; off >>= 1)
            acc[e] += __shfl_down(acc[e], off, 64);

    if (lane == 0) {
        float lg[NE];
#pragma unroll
        for (int e = 0; e < NE; e++) lg[e] = acc[e] + br[e];
        int i0 = 0;
        for (int e = 1; e < NE; e++) if (lg[e] > lg[i0]) i0 = e;
        int i1 = (i0 == 0) ? 1 : 0;
        for (int e = 0; e < NE; e++) if (e != i0 && lg[e] > lg[i1]) i1 = e;
        float g0 = 1.f / (1.f + expf(lg[i1] - lg[i0]));  // renormalized top-2 softmax
        atomicAdd(&cnt[i0], 1);
        atomicAdd(&cnt[i1], 1);
        meta_i[t] = i0 | (i1 << 8);
        meta_g[t] = g0;
    }
}

// ---------------- scan ----------------
__global__ void scan_kernel(const int* __restrict__ cnt, int* __restrict__ offs,
                            int* __restrict__ pos)
{
    if (threadIdx.x == 0) {
        int o = 0;
        for (int e = 0; e < NE; e++) { offs[e] = o; pos[e] = o; o += cnt[e]; }
    }
}

// ---------------- scatter ----------------
__global__ __launch_bounds__(256)
void scatter_kernel(const float* __restrict__ x, const int* __restrict__ meta_i,
                    int* __restrict__ pos, int* __restrict__ tslot,
                    ushort* __restrict__ Xg)
{
    const int t    = (blockIdx.x * blockDim.x + threadIdx.x) >> 6;
    const int lane = threadIdx.x & 63;
    if (t >= TT) return;
    int s0 = 0, s1 = 0;
    if (lane == 0) {
        int mi = meta_i[t];
        int i0 = mi & 0xff, i1 = (mi >> 8) & 0xff;
        s0 = atomicAdd(&pos[i0], 1);
        s1 = atomicAdd(&pos[i1], 1);
        tslot[t] = s0 | (s1 << 16);
    }
    s0 = __shfl(s0, 0, 64);
    s1 = __shfl(s1, 0, 64);
    const float4* xr = (const float4*)(x + (size_t)t * DM);
#pragma unroll
    for (int i = 0; i < 4; i++) {
        float4 v = xr[lane + 64 * i];
        uint2 pv = make_uint2(pkbf(v.x, v.y), pkbf(v.z, v.w));
        *(uint2*)(Xg + (size_t)s0 * DM + (lane + 64 * i) * 4) = pv;
        *(uint2*)(Xg + (size_t)s1 * DM + (lane + 64 * i) * 4) = pv;
    }
}

// ---------------- wconv: W[e][K][F] fp32 -> Wt[e][F][K] bf16 ----------------
__global__ __launch_bounds__(256)
void wconv_kernel(const float* __restrict__ W, ushort* __restrict__ Wt, int K, int F)
{
    const int e  = blockIdx.z;
    const int k0 = blockIdx.y * 64, f0 = blockIdx.x * 64;
    const float* We = W + (size_t)e * K * F;
    ushort* Oe = Wt + (size_t)e * K * F;

    __shared__ char lds[64 * 136];

    const int tid = threadIdx.x;
    const int a = tid & 15, b = tid >> 4;

    const float* src = We + (size_t)(k0 + b * 4) * F + f0 + a * 4;
    float4 v0 = *(const float4*)(src);
    float4 v1 = *(const float4*)(src + F);
    float4 v2 = *(const float4*)(src + 2 * F);
    float4 v3 = *(const float4*)(src + 3 * F);
    const float* p0 = (const float*)&v0; const float* p1 = (const float*)&v1;
    const float* p2 = (const float*)&v2; const float* p3 = (const float*)&v3;
#pragma unroll
    for (int j = 0; j < 4; j++) {
        int f = a * 4 + j;
        uint2 pv = make_uint2(pkbf(p0[j], p1[j]), pkbf(p2[j], p3[j]));
        *(uint2*)(lds + f * 136 + ((b ^ a) * 8)) = pv;
    }
    __syncthreads();
#pragma unroll
    for (int i = 0; i < 2; i++) {
        int idx = tid + 256 * i;
        int fl = idx >> 3, kc = idx & 7;
        int xw = fl >> 2;
        uint2 lo = *(const uint2*)(lds + fl * 136 + (((kc * 2)     ^ xw) * 8));
        uint2 hi = *(const uint2*)(lds + fl * 136 + (((kc * 2 + 1) ^ xw) * 8));
        uint4 o = make_uint4(lo.x, lo.y, hi.x, hi.y);
        *(uint4*)(Oe + (size_t)(f0 + fl) * K + k0 + kc * 8) = o;
    }
}

// ---------------- GEMM1: H = relu(Xg @ W1t^T + b1), ring-4 counted-vmcnt ----------------
__global__ __launch_bounds__(512)
void gemm1_kernel(const ushort* __restrict__ Xg, const ushort* __restrict__ W1t,
                  const float* __restrict__ b1, const int* __restrict__ cnt,
                  const int* __restrict__ offs, ushort* __restrict__ H)
{
    // T1: bijective XCD swizzle — each XCD owns one expert (z) slice.
    int id = blockIdx.x + (blockIdx.y << 4) + (blockIdx.z << 7);   // grid (16,8,8)
    int sw = ((id & 7) << 7) + (id >> 3);
    const int bx = sw & 15, by = (sw >> 4) & 7, bz = sw >> 7;

    const int e = bz;
    const int n_e = cnt[e];
    const int t0 = by * 256;
    if (t0 >= n_e) return;
    const int ft0 = bx * 256;
    const int slot0 = offs[e] + t0;
    const ushort* Be = W1t + (size_t)e * DF * DM;   // [f][k]

    __shared__ char smem[131072];   // 4 ring buffers x (A 16K | B 16K)

    const int tid = threadIdx.x;
    const int l = tid & 63, wid = tid >> 6;
    const int wm = (wid >> 2) * 128, wn = (wid & 3) * 64;
    const int lm = l & 15, q = l >> 4;

    f32x4 acc[8][4];
#pragma unroll
    for (int i = 0; i < 8; i++)
#pragma unroll
        for (int j = 0; j < 4; j++) acc[i][j] = (f32x4){0.f, 0.f, 0.f, 0.f};

    const int NT = DM / 32;   // 32
    // prologue: stage tiles 0..2 (12 gll16/thread in flight)
    stage32(Xg, slot0, DM, Be, ft0, DM, 0,  smem,          tid);
    __builtin_amdgcn_sched_barrier(0);
    stage32(Xg, slot0, DM, Be, ft0, DM, 32, smem + 32768,  tid);
    __builtin_amdgcn_sched_barrier(0);
    stage32(Xg, slot0, DM, Be, ft0, DM, 64, smem + 65536,  tid);
    __builtin_amdgcn_sched_barrier(0);

    for (int kt = 0; kt < NT; ++kt) {
        // counted wait: retire oldest tile's 4 loads, keep the rest in flight (T4)
        if (kt < NT - 2)       asm volatile("s_waitcnt vmcnt(8)" ::: "memory");
        else if (kt == NT - 2) asm volatile("s_waitcnt vmcnt(4)" ::: "memory");
        else                   asm volatile("s_waitcnt vmcnt(0)" ::: "memory");
        __builtin_amdgcn_sched_barrier(0);
        __builtin_amdgcn_s_barrier();
        __builtin_amdgcn_sched_barrier(0);
        if (kt + 3 < NT)
            stage32(Xg, slot0, DM, Be, ft0, DM, (kt + 3) * 32,
                    smem + ((kt + 3) & 3) * 32768, tid);
        const char* Ab = smem + (kt & 3) * 32768;
        const char* Bb = Ab + 16384;
        bf16x8 af[8], bfr[4];
#pragma unroll
        for (int i = 0; i < 8; i++) af[i] = *fragp(Ab, wm + i * 16 + lm, q);
#pragma unroll
        for (int j = 0; j < 4; j++) bfr[j] = *fragp(Bb, wn + j * 16 + lm, q);
        __builtin_amdgcn_s_setprio(1);
#pragma unroll
        for (int i = 0; i < 8; i++)
#pragma unroll
            for (int j = 0; j < 4; j++)
                acc[i][j] = __builtin_amdgcn_mfma_f32_16x16x32_bf16(af[i], bfr[j], acc[i][j], 0, 0, 0);
        __builtin_amdgcn_s_setprio(0);
    }

    // epilogue: relu(+b1) -> bf16 H via LDS bounce, 4 stripes of 64 rows
    float b1v[4];
#pragma unroll
    for (int j = 0; j < 4; j++) b1v[j] = b1[e * DF + ft0 + wn + j * 16 + lm];

    float* Cb = (float*)smem;   // [64][264]
    __syncthreads();
#pragma unroll
    for (int s4 = 0; s4 < 4; s4++) {
        if ((wid >> 2) == (s4 >> 1)) {
#pragma unroll
            for (int i = 0; i < 4; i++) {
                int mi = (s4 & 1) * 4 + i;
#pragma unroll
                for (int j = 0; j < 4; j++)
#pragma unroll
                    for (int r = 0; r < 4; r++) {
                        int lr = i * 16 + q * 4 + r;
                        Cb[lr * 264 + wn + j * 16 + lm] = fmaxf(acc[mi][j][r] + b1v[j], 0.f);
                    }
            }
        }
        __syncthreads();
        {
            int row = tid >> 3, seg = tid & 7;
            // GUARD: partial tiles must not write H rows of the next expert's slots
            if (t0 + s4 * 64 + row < n_e) {
                size_t hb = (size_t)(slot0 + s4 * 64 + row) * DF + ft0 + seg * 32;
#pragma unroll
                for (int i = 0; i < 4; i++) {
                    float4 a = *(const float4*)&Cb[row * 264 + seg * 32 + i * 8];
                    float4 b = *(const float4*)&Cb[row * 264 + seg * 32 + i * 8 + 4];
                    uint4 o;
                    o.x = pkbf(a.x, a.y); o.y = pkbf(a.z, a.w);
                    o.z = pkbf(b.x, b.y); o.w = pkbf(b.z, b.w);
                    *(uint4*)(H + hb + i * 8) = o;
                }
            }
        }
        __syncthreads();
    }
}

// ---------------- GEMM2: Y[kz] = H @ W2t^T (+b2 on kz=0), ring-4 counted-vmcnt ----------------
__global__ __launch_bounds__(512)
void gemm2_kernel(const ushort* __restrict__ H, const ushort* __restrict__ W2t,
                  const float* __restrict__ b2, const int* __restrict__ cnt,
                  const int* __restrict__ offs, float* __restrict__ Y)
{
    // T1: XCD swizzle — each XCD owns one expert (both kz halves).
    int id = blockIdx.x + (blockIdx.y << 2) + (blockIdx.z << 5);   // grid (4,8,16)
    int sw = ((id & 7) << 6) + (id >> 3);
    const int bx = sw & 3, by = (sw >> 2) & 7, bz = sw >> 5;

    const int e  = bz >> 1;
    const int kz = bz & 1;
    const int n_e = cnt[e];
    const int t0 = by * 256;
    if (t0 >= n_e) return;
    const int nt0 = bx * 256;
    const int slot0 = offs[e] + t0;
    const ushort* Be = W2t + (size_t)e * DM * DF;   // [d][k]

    __shared__ char smem[131072];

    const int tid = threadIdx.x;
    const int l = tid & 63, wid = tid >> 6;
    const int wm = (wid >> 2) * 128, wn = (wid & 3) * 64;
    const int lm = l & 15, q = l >> 4;

    f32x4 acc[8][4];
#pragma unroll
    for (int i = 0; i < 8; i++)
#pragma unroll
        for (int j = 0; j < 4; j++) acc[i][j] = (f32x4){0.f, 0.f, 0.f, 0.f};

    const int kbeg = kz * (DF / 2);
    const int NT = (DF / 2) / 32;   // 64
    stage32(H, slot0, DF, Be, nt0, DF, kbeg,      smem,         tid);
    __builtin_amdgcn_sched_barrier(0);
    stage32(H, slot0, DF, Be, nt0, DF, kbeg + 32, smem + 32768, tid);
    __builtin_amdgcn_sched_barrier(0);
    stage32(H, slot0, DF, Be, nt0, DF, kbeg + 64, smem + 65536, tid);
    __builtin_amdgcn_sched_barrier(0);

    for (int kt = 0; kt < NT; ++kt) {
        if (kt < NT - 2)       asm volatile("s_waitcnt vmcnt(8)" ::: "memory");
        else if (kt == NT - 2) asm volatile("s_waitcnt vmcnt(4)" ::: "memory");
        else                   asm volatile("s_waitcnt vmcnt(0)" ::: "memory");
        __builtin_amdgcn_sched_barrier(0);
        __builtin_amdgcn_s_barrier();
        __builtin_amdgcn_sched_barrier(0);
        if (kt + 3 < NT)
            stage32(H, slot0, DF, Be, nt0, DF, kbeg + (kt + 3) * 32,
                    smem + ((kt + 3) & 3) * 32768, tid);
        const char* Ab = smem + (kt & 3) * 32768;
        const char* Bb = Ab + 16384;
        bf16x8 af[8], bfr[4];
#pragma unroll
        for (int i = 0; i < 8; i++) af[i] = *fragp(Ab, wm + i * 16 + lm, q);
#pragma unroll
        for (int j = 0; j < 4; j++) bfr[j] = *fragp(Bb, wn + j * 16 + lm, q);
        __builtin_amdgcn_s_setprio(1);
#pragma unroll
        for (int i = 0; i < 8; i++)
#pragma unroll
            for (int j = 0; j < 4; j++)
                acc[i][j] = __builtin_amdgcn_mfma_f32_16x16x32_bf16(af[i], bfr[j], acc[i][j], 0, 0, 0);
        __builtin_amdgcn_s_setprio(0);
    }

    float b2v[4];
#pragma unroll
    for (int j = 0; j < 4; j++)
        b2v[j] = (kz == 0) ? b2[e * DM + nt0 + wn + j * 16 + lm] : 0.f;

    float* Ye = Y + (size_t)kz * NSLOT * DM;
#pragma unroll
    for (int i = 0; i < 8; i++)
#pragma unroll
        for (int r = 0; r < 4; r++) {
            int mrow = wm + i * 16 + q * 4 + r;
            if (t0 + mrow < n_e) {   // GUARD: no cross-expert slot writes
                float* yrow = Ye + (size_t)(slot0 + mrow) * DM + nt0;
#pragma unroll
                for (int j = 0; j < 4; j++)
                    yrow[wn + j * 16 + lm] = acc[i][j][r] + b2v[j];
            }
        }
}

// ---------------- combine ----------------
__global__ __launch_bounds__(256)
void combine_kernel(const float* __restrict__ Y, const int* __restrict__ tslot,
                    const float* __restrict__ metaG, float4* __restrict__ out)
{
    const int t = blockIdx.x;
    const int c = threadIdx.x;
    int ts = tslot[t];
    int s0 = ts & 0xffff, s1 = (ts >> 16) & 0xffff;
    float g0 = metaG[t], g1 = 1.f - g0;
    const float4* Y0 = (const float4*)Y;
    const float4* Y1 = (const float4*)(Y + (size_t)NSLOT * DM);
    float4 a0 = Y0[(size_t)s0 * (DM / 4) + c];
    float4 a1 = Y1[(size_t)s0 * (DM / 4) + c];
    float4 c0 = Y0[(size_t)s1 * (DM / 4) + c];
    float4 c1 = Y1[(size_t)s1 * (DM / 4) + c];
    float4 o;
    o.x = g0 * (a0.x + a1.x) + g1 * (c0.x + c1.x);
    o.y = g0 * (a0.y + a1.y) + g1 * (c0.y + c1.y);
    o.z = g0 * (a0.z + a1.z) + g1 * (c0.z + c1.z);
    o.w = g0 * (a0.w + a1.w) + g1 * (c0.w + c1.w);
    out[(size_t)t * (DM / 4) + c] = o;
}

extern "C" void kernel_launch(void* const* d_in, const int* in_sizes, int n_in,
                              void* d_out, int out_size, void* d_ws, size_t ws_size,
                              hipStream_t stream)
{
    const float* x  = (const float*)d_in[0];
    const float* Wr = (const float*)d_in[1];
    const float* br = (const float*)d_in[2];
    const float* W1 = (const float*)d_in[3];
    const float* b1 = (const float*)d_in[4];
    const float* W2 = (const float*)d_in[5];
    const float* b2 = (const float*)d_in[6];
    float* out = (float*)d_out;

    char* ws = (char*)d_ws;
    int*    cnt   = (int*)(ws + CNT_OFF);
    int*    offs  = (int*)(ws + OFFS_OFF);
    int*    pos   = (int*)(ws + POS_OFF);
    int*    metaI = (int*)(ws + METAI_OFF);
    float*  metaG = (float*)(ws + METAG_OFF);
    int*    tslot = (int*)(ws + TSLOT_OFF);
    ushort* Xg    = (ushort*)(ws + XG_OFF);
    ushort* W1t   = (ushort*)(ws + W1T_OFF);
    ushort* H     = (ushort*)(ws + H_OFF);
    ushort* W2t   = (ushort*)(ws + W2T_OFF);
    float*  Y     = (float*)(ws + Y_OFF);     // aliases Xg+W1t (both dead after gemm1)

    init_kernel<<<1, 64, 0, stream>>>(cnt);
    wconv_kernel<<<dim3(DF / 64, DM / 64, NE), 256, 0, stream>>>(W1, W1t, DM, DF);
    wconv_kernel<<<dim3(DM / 64, DF / 64, NE), 256, 0, stream>>>(W2, W2t, DF, DM);
    router_kernel<<<TT / 4, 256, 0, stream>>>(x, Wr, br, cnt, metaI, metaG);
    scan_kernel<<<1, 64, 0, stream>>>(cnt, offs, pos);
    scatter_kernel<<<TT / 4, 256, 0, stream>>>(x, metaI, pos, tslot, Xg);

    gemm1_kernel<<<dim3(16, 8, 8), 512, 0, stream>>>(Xg, W1t, b1, cnt, offs, H);
    gemm2_kernel<<<dim3(4, 8, 16), 512, 0, stream>>>(H, W2t, b2, cnt, offs, Y);
    combine_kernel<<<TT, 256, 0, stream>>>(Y, tslot, metaG, (float4*)out);
}

// Round 4
// 718.306 us; speedup vs baseline: 1.0422x; 1.0422x over previous
//
#include <hip/hip_runtime.h>

#define TT 4096      // tokens
#define DM 1024      // d_model
#define DF 4096      // d_ff
#define NE 8         // experts
#define NSLOT 8192   // exactly 2*TT slots; M-overreach spills into adjacent ws (masked)

typedef short bf16x8 __attribute__((ext_vector_type(8)));
typedef float f32x4  __attribute__((ext_vector_type(4)));

// ---------- ws layout (bytes), total 218,234,880 (round-2 size, known OK) ----------
#define CNT_OFF    0
#define OFFS_OFF   256
#define POS_OFF    512
#define METAI_OFF  4096                       // int[TT]
#define METAG_OFF  (METAI_OFF + 4*TT)         // float[TT]
#define TSLOT_OFF  (METAG_OFF + 4*TT)         // int[TT]  (s0 | s1<<16)
#define XG_OFF     131072                     // ushort[NSLOT*DM]   (dead after gemm1)
#define W1T_OFF    (XG_OFF + 2*NSLOT*DM)      // ushort[NE*DF*DM] bf16 [e][f][k] (dead after gemm1)
#define H_OFF      (W1T_OFF + 2*NE*DM*DF)     // ushort[NSLOT*DF]
#define W2T_OFF    (H_OFF + 2*NSLOT*DF)       // ushort[NE*DM*DF] bf16 [e][d][k]
#define Y_OFF      XG_OFF                     // float[2][NSLOT*DM] aliases Xg+W1t

// fp32 pair -> packed bf16x2 (RNE)
__device__ __forceinline__ unsigned pkbf(float a, float b) {
    unsigned ua = __float_as_uint(a), ub = __float_as_uint(b);
    ua += 0x7fffu + ((ua >> 16) & 1u);
    ub += 0x7fffu + ((ub >> 16) & 1u);
    return __builtin_amdgcn_perm(ub, ua, 0x07060302u);
}

// async global->LDS, 16B per lane; LDS dest linear (wave-uniform base + lane*16)
__device__ __forceinline__ void gll16(const void* g, void* l) {
    __builtin_amdgcn_global_load_lds(
        (const __attribute__((address_space(1))) void*)g,
        (__attribute__((address_space(3))) void*)l, 16, 0, 0);
}

// stage one 128-row x 64-k bf16 half-tile (16KB): linear LDS dest, inverse-XOR
// swizzled global source (read key = row&7). 2 gll16 per thread (512 thr).
__device__ __forceinline__ void stage_half(const ushort* __restrict__ base, int row0,
                                           int stride, int k0, char* dst, int tid)
{
#pragma unroll
    for (int i = 0; i < 2; i++) {
        int cid = i * 512 + tid;
        int row = cid >> 3, c = (cid & 7) ^ (row & 7);
        gll16(base + (size_t)(row0 + row) * stride + k0 + c * 8, dst + cid * 16);
    }
}

// ---------------- init ----------------
__global__ void init_kernel(int* __restrict__ cnt)
{
    if (threadIdx.x < NE) cnt[threadIdx.x] = 0;
}

// ---------------- Router ----------------
__global__ __launch_bounds__(256)
void router_kernel(const float* __restrict__ x, const float* __restrict__ Wr,
                   const float* __restrict__ br,
                   int* __restrict__ cnt, int* __restrict__ meta_i,
                   float* __restrict__ meta_g)
{
    const int t    = (blockIdx.x * blockDim.x + threadIdx.x) >> 6;
    const int lane = threadIdx.x & 63;
    if (t >= TT) return;
    const float* xr = x + (size_t)t * DM;

    float acc[NE];
#pragma unroll
    for (int e = 0; e < NE; e++) acc[e] = 0.f;
    for (int i = 0; i < DM / 64; i++) {
        int d = lane + (i << 6);
        float xv = xr[d];
        const float4* wr = (const float4*)(Wr + (size_t)d * NE);
        float4 w0 = wr[0], w1 = wr[1];
        acc[0] += xv * w0.x; acc[1] += xv * w0.y;
        acc[2] += xv * w0.z; acc[3] += xv * w0.w;
        acc[4] += xv * w1.x; acc[5] += xv * w1.y;
        acc[6] += xv * w1.z; acc[7] += xv * w1.w;
    }
#pragma unroll
    for (int e = 0; e < NE; e++)
#pragma unroll
        for (int off = 32; off > 0; off >>= 1)
            acc[e] += __shfl_down(acc[e], off, 64);

    if (lane == 0) {
        float lg[NE];
#pragma unroll
        for (int e = 0; e < NE; e++) lg[e] = acc[e] + br[e];
        int i0 = 0;
        for (int e = 1; e < NE; e++) if (lg[e] > lg[i0]) i0 = e;
        int i1 = (i0 == 0) ? 1 : 0;
        for (int e = 0; e < NE; e++) if (e != i0 && lg[e] > lg[i1]) i1 = e;
        float g0 = 1.f / (1.f + expf(lg[i1] - lg[i0]));  // renormalized top-2 softmax
        atomicAdd(&cnt[i0], 1);
        atomicAdd(&cnt[i1], 1);
        meta_i[t] = i0 | (i1 << 8);
        meta_g[t] = g0;
    }
}

// ---------------- scan ----------------
__global__ void scan_kernel(const int* __restrict__ cnt, int* __restrict__ offs,
                            int* __restrict__ pos)
{
    if (threadIdx.x == 0) {
        int o = 0;
        for (int e = 0; e < NE; e++) { offs[e] = o; pos[e] = o; o += cnt[e]; }
    }
}

// ---------------- scatter ----------------
__global__ __launch_bounds__(256)
void scatter_kernel(const float* __restrict__ x, const int* __restrict__ meta_i,
                    int* __restrict__ pos, int* __restrict__ tslot,
                    ushort* __restrict__ Xg)
{
    const int t    = (blockIdx.x * blockDim.x + threadIdx.x) >> 6;
    const int lane = threadIdx.x & 63;
    if (t >= TT) return;
    int s0 = 0, s1 = 0;
    if (lane == 0) {
        int mi = meta_i[t];
        int i0 = mi & 0xff, i1 = (mi >> 8) & 0xff;
        s0 = atomicAdd(&pos[i0], 1);
        s1 = atomicAdd(&pos[i1], 1);
        tslot[t] = s0 | (s1 << 16);
    }
    s0 = __shfl(s0, 0, 64);
    s1 = __shfl(s1, 0, 64);
    const float4* xr = (const float4*)(x + (size_t)t * DM);
#pragma unroll
    for (int i = 0; i < 4; i++) {
        float4 v = xr[lane + 64 * i];
        uint2 pv = make_uint2(pkbf(v.x, v.y), pkbf(v.z, v.w));
        *(uint2*)(Xg + (size_t)s0 * DM + (lane + 64 * i) * 4) = pv;
        *(uint2*)(Xg + (size_t)s1 * DM + (lane + 64 * i) * 4) = pv;
    }
}

// ---------------- wconv: W[e][K][F] fp32 -> Wt[e][F][K] bf16 ----------------
__global__ __launch_bounds__(256)
void wconv_kernel(const float* __restrict__ W, ushort* __restrict__ Wt, int K, int F)
{
    const int e  = blockIdx.z;
    const int k0 = blockIdx.y * 64, f0 = blockIdx.x * 64;
    const float* We = W + (size_t)e * K * F;
    ushort* Oe = Wt + (size_t)e * K * F;

    __shared__ char lds[64 * 136];

    const int tid = threadIdx.x;
    const int a = tid & 15, b = tid >> 4;

    const float* src = We + (size_t)(k0 + b * 4) * F + f0 + a * 4;
    float4 v0 = *(const float4*)(src);
    float4 v1 = *(const float4*)(src + F);
    float4 v2 = *(const float4*)(src + 2 * F);
    float4 v3 = *(const float4*)(src + 3 * F);
    const float* p0 = (const float*)&v0; const float* p1 = (const float*)&v1;
    const float* p2 = (const float*)&v2; const float* p3 = (const float*)&v3;
#pragma unroll
    for (int j = 0; j < 4; j++) {
        int f = a * 4 + j;
        uint2 pv = make_uint2(pkbf(p0[j], p1[j]), pkbf(p2[j], p3[j]));
        *(uint2*)(lds + f * 136 + ((b ^ a) * 8)) = pv;
    }
    __syncthreads();
#pragma unroll
    for (int i = 0; i < 2; i++) {
        int idx = tid + 256 * i;
        int fl = idx >> 3, kc = idx & 7;
        int xw = fl >> 2;
        uint2 lo = *(const uint2*)(lds + fl * 136 + (((kc * 2)     ^ xw) * 8));
        uint2 hi = *(const uint2*)(lds + fl * 136 + (((kc * 2 + 1) ^ xw) * 8));
        uint4 o = make_uint4(lo.x, lo.y, hi.x, hi.y);
        *(uint4*)(Oe + (size_t)(f0 + fl) * K + k0 + kc * 8) = o;
    }
}

// ============= shared GEMM core macros: 4 quadrant-phases per K-tile =============
// LDS per dbuf (64KB): AL @0, AH @16K, BL @32K, BH @48K. 2 dbufs = 128KB.
// Phase p reads only new frags (A/B halves persist in regs); stages 1 half of
// T+1 into other dbuf; counted vmcnt never drains in-loop.

#define FENCE asm volatile("" ::: "memory")

#define READ_A(HALF)                                                           \
_Pragma("unroll")                                                              \
    for (int ii = 0; ii < 4; ii++)                                             \
_Pragma("unroll")                                                              \
        for (int s = 0; s < 2; s++)                                            \
            af[ii][s] = *(const bf16x8*)(db + (HALF) * 16384 + offA[ii][s]);

#define READ_B(DST, HALF)                                                      \
_Pragma("unroll")                                                              \
    for (int jj = 0; jj < 2; jj++)                                             \
_Pragma("unroll")                                                              \
        for (int s = 0; s < 2; s++)                                            \
            DST[jj][s] = *(const bf16x8*)(db + 32768 + (HALF) * 16384 + offB[jj][s]);

#define MMCL(QR, QC, BSRC)                                                     \
    __builtin_amdgcn_s_setprio(1);                                             \
_Pragma("unroll")                                                              \
    for (int s = 0; s < 2; s++)                                                \
_Pragma("unroll")                                                              \
        for (int ii = 0; ii < 4; ii++)                                         \
_Pragma("unroll")                                                              \
            for (int jj = 0; jj < 2; jj++)                                     \
                acc[QR][QC][ii][jj] = __builtin_amdgcn_mfma_f32_16x16x32_bf16( \
                    af[ii][s], BSRC[jj][s], acc[QR][QC][ii][jj], 0, 0, 0);     \
    __builtin_amdgcn_s_setprio(0);

// ---------------- GEMM1: H = relu(Xg @ W1t^T + b1) ----------------
__global__ __launch_bounds__(512)
void gemm1_kernel(const ushort* __restrict__ Xg, const ushort* __restrict__ W1t,
                  const float* __restrict__ b1, const int* __restrict__ cnt,
                  const int* __restrict__ offs, ushort* __restrict__ H)
{
    const int wg = blockIdx.x;           // flat id: e = wg&7 -> XCD-pinned expert
    const int e  = wg & 7;
    const int rr_ = wg >> 3;
    const int ft0 = (rr_ & 15) * 256;
    const int t0  = (rr_ >> 4) * 256;    // covers up to 4096 rows (safe imbalance)
    const int n_e = cnt[e];
    if (t0 >= n_e) return;
    const int slot0 = offs[e] + t0;
    const ushort* Be = W1t + (size_t)e * DF * DM;   // [f][k]

    __shared__ char smem[131072];

    const int tid = threadIdx.x;
    const int l = tid & 63, wid = tid >> 6;
    const int ar = wid >> 2, ac = wid & 3;          // wave = 64x32 subtile per quadrant
    const int lm = l & 15, q = l >> 4;

    int offA[4][2], offB[2][2];
#pragma unroll
    for (int ii = 0; ii < 4; ii++)
#pragma unroll
        for (int s = 0; s < 2; s++) {
            int rw = ar * 64 + ii * 16 + lm;
            offA[ii][s] = rw * 128 + ((((s << 2) | q) ^ (rw & 7)) * 16);
        }
#pragma unroll
    for (int jj = 0; jj < 2; jj++)
#pragma unroll
        for (int s = 0; s < 2; s++) {
            int cw = ac * 32 + jj * 16 + lm;
            offB[jj][s] = cw * 128 + ((((s << 2) | q) ^ (cw & 7)) * 16);
        }

    f32x4 acc[2][2][4][2];
#pragma unroll
    for (int a0 = 0; a0 < 2; a0++)
#pragma unroll
        for (int b0 = 0; b0 < 2; b0++)
#pragma unroll
            for (int ii = 0; ii < 4; ii++)
#pragma unroll
                for (int jj = 0; jj < 2; jj++)
                    acc[a0][b0][ii][jj] = (f32x4){0.f, 0.f, 0.f, 0.f};

    // prologue: T0 halves, issue order AL,BL,BH,AH (= retirement ledger order)
    stage_half(Xg, slot0,       DM, 0, smem,          tid);
    stage_half(Be, ft0,         DM, 0, smem + 32768,  tid);
    stage_half(Be, ft0 + 128,   DM, 0, smem + 49152,  tid);
    stage_half(Xg, slot0 + 128, DM, 0, smem + 16384,  tid);

    bf16x8 af[4][2], bl[2][2], bh[2][2];
    const int NT = DM / 64;   // 16
#pragma unroll 2
    for (int kt = 0; kt < NT; ++kt) {
        const char* db = smem + (kt & 1) * 65536;
        char* sb = smem + ((kt & 1) ^ 1) * 65536;
        const int kn = (kt + 1) * 64;
        const bool st = (kt + 1 < NT);
        // ---- phase 1: quadrant (0,0); needs T.AL,T.BL ----
        asm volatile("s_waitcnt vmcnt(4)" ::: "memory");
        __builtin_amdgcn_s_barrier(); FENCE;
        READ_A(0); READ_B(bl, 0);
        if (st) stage_half(Xg, slot0, DM, kn, sb, tid);            // T+1.AL
        MMCL(0, 0, bl);
        // ---- phase 2: (0,1); needs T.BH ----
        if (st) { asm volatile("s_waitcnt vmcnt(4)" ::: "memory"); }
        else    { asm volatile("s_waitcnt vmcnt(2)" ::: "memory"); }
        __builtin_amdgcn_s_barrier(); FENCE;
        READ_B(bh, 1);
        if (st) stage_half(Be, ft0, DM, kn, sb + 32768, tid);      // T+1.BL
        MMCL(0, 1, bh);
        // ---- phase 3: (1,0); needs T.AH ----
        if (st) { asm volatile("s_waitcnt vmcnt(4)" ::: "memory"); }
        else    { asm volatile("s_waitcnt vmcnt(0)" ::: "memory"); }
        __builtin_amdgcn_s_barrier(); FENCE;
        READ_A(1);
        if (st) stage_half(Be, ft0 + 128, DM, kn, sb + 49152, tid); // T+1.BH
        MMCL(1, 0, bl);
        // ---- phase 4: (1,1); register-only ----
        if (st) stage_half(Xg, slot0 + 128, DM, kn, sb + 16384, tid); // T+1.AH
        MMCL(1, 1, bh);
    }
    __syncthreads();

    // epilogue: relu(+b1) -> bf16 H via LDS bounce, 4 stripes of 64 rows
    float b1v[2][2];
#pragma unroll
    for (int qc = 0; qc < 2; qc++)
#pragma unroll
        for (int jj = 0; jj < 2; jj++)
            b1v[qc][jj] = b1[e * DF + ft0 + qc * 128 + ac * 32 + jj * 16 + lm];

    float* Cb = (float*)smem;   // [64][264]
#pragma unroll
    for (int s4 = 0; s4 < 4; s4++) {
        if (ar == (s4 & 1)) {
            const int qr = s4 >> 1;
#pragma unroll
            for (int qc = 0; qc < 2; qc++)
#pragma unroll
                for (int ii = 0; ii < 4; ii++)
#pragma unroll
                    for (int jj = 0; jj < 2; jj++)
#pragma unroll
                        for (int rr = 0; rr < 4; rr++) {
                            int lr  = ii * 16 + q * 4 + rr;
                            int col = qc * 128 + ac * 32 + jj * 16 + lm;
                            Cb[lr * 264 + col] = fmaxf(acc[qr][qc][ii][jj][rr] + b1v[qc][jj], 0.f);
                        }
        }
        __syncthreads();
#pragma unroll
        for (int c4 = 0; c4 < 4; c4++) {
            int idx = c4 * 512 + tid;
            int row = idx >> 5, ch = idx & 31;
            // GUARD: partial tiles must not write H rows of the next expert's slots
            if (t0 + s4 * 64 + row < n_e) {
                const float* src = &Cb[row * 264 + ch * 8];
                float4 a = *(const float4*)src;
                float4 b = *(const float4*)(src + 4);
                uint4 o;
                o.x = pkbf(a.x, a.y); o.y = pkbf(a.z, a.w);
                o.z = pkbf(b.x, b.y); o.w = pkbf(b.z, b.w);
                *(uint4*)(H + (size_t)(slot0 + s4 * 64 + row) * DF + ft0 + ch * 8) = o;
            }
        }
        __syncthreads();
    }
}

// ---------------- GEMM2: Y[kz] = H @ W2t^T (+b2 on kz=0) ----------------
__global__ __launch_bounds__(512)
void gemm2_kernel(const ushort* __restrict__ H, const ushort* __restrict__ W2t,
                  const float* __restrict__ b2, const int* __restrict__ cnt,
                  const int* __restrict__ offs, float* __restrict__ Y)
{
    const int wg = blockIdx.x;           // e = wg&7 -> XCD-pinned (both kz halves)
    const int e  = wg & 7;
    const int rr_ = wg >> 3;
    const int kz  = rr_ & 1;
    const int nt0 = ((rr_ >> 1) & 3) * 256;
    const int t0  = (rr_ >> 3) * 256;
    const int n_e = cnt[e];
    if (t0 >= n_e) return;
    const int slot0 = offs[e] + t0;
    const ushort* Be = W2t + (size_t)e * DM * DF;   // [d][k]

    __shared__ char smem[131072];

    const int tid = threadIdx.x;
    const int l = tid & 63, wid = tid >> 6;
    const int ar = wid >> 2, ac = wid & 3;
    const int lm = l & 15, q = l >> 4;

    int offA[4][2], offB[2][2];
#pragma unroll
    for (int ii = 0; ii < 4; ii++)
#pragma unroll
        for (int s = 0; s < 2; s++) {
            int rw = ar * 64 + ii * 16 + lm;
            offA[ii][s] = rw * 128 + ((((s << 2) | q) ^ (rw & 7)) * 16);
        }
#pragma unroll
    for (int jj = 0; jj < 2; jj++)
#pragma unroll
        for (int s = 0; s < 2; s++) {
            int cw = ac * 32 + jj * 16 + lm;
            offB[jj][s] = cw * 128 + ((((s << 2) | q) ^ (cw & 7)) * 16);
        }

    f32x4 acc[2][2][4][2];
#pragma unroll
    for (int a0 = 0; a0 < 2; a0++)
#pragma unroll
        for (int b0 = 0; b0 < 2; b0++)
#pragma unroll
            for (int ii = 0; ii < 4; ii++)
#pragma unroll
                for (int jj = 0; jj < 2; jj++)
                    acc[a0][b0][ii][jj] = (f32x4){0.f, 0.f, 0.f, 0.f};

    const int kbeg = kz * (DF / 2);
    stage_half(H,  slot0,       DF, kbeg, smem,          tid);
    stage_half(Be, nt0,         DF, kbeg, smem + 32768,  tid);
    stage_half(Be, nt0 + 128,   DF, kbeg, smem + 49152,  tid);
    stage_half(H,  slot0 + 128, DF, kbeg, smem + 16384,  tid);

    bf16x8 af[4][2], bl[2][2], bh[2][2];
    const int NT = (DF / 2) / 64;   // 32
#pragma unroll 2
    for (int kt = 0; kt < NT; ++kt) {
        const char* db = smem + (kt & 1) * 65536;
        char* sb = smem + ((kt & 1) ^ 1) * 65536;
        const int kn = kbeg + (kt + 1) * 64;
        const bool st = (kt + 1 < NT);
        asm volatile("s_waitcnt vmcnt(4)" ::: "memory");
        __builtin_amdgcn_s_barrier(); FENCE;
        READ_A(0); READ_B(bl, 0);
        if (st) stage_half(H, slot0, DF, kn, sb, tid);             // T+1.AL
        MMCL(0, 0, bl);
        if (st) { asm volatile("s_waitcnt vmcnt(4)" ::: "memory"); }
        else    { asm volatile("s_waitcnt vmcnt(2)" ::: "memory"); }
        __builtin_amdgcn_s_barrier(); FENCE;
        READ_B(bh, 1);
        if (st) stage_half(Be, nt0, DF, kn, sb + 32768, tid);      // T+1.BL
        MMCL(0, 1, bh);
        if (st) { asm volatile("s_waitcnt vmcnt(4)" ::: "memory"); }
        else    { asm volatile("s_waitcnt vmcnt(0)" ::: "memory"); }
        __builtin_amdgcn_s_barrier(); FENCE;
        READ_A(1);
        if (st) stage_half(Be, nt0 + 128, DF, kn, sb + 49152, tid); // T+1.BH
        MMCL(1, 0, bl);
        if (st) stage_half(H, slot0 + 128, DF, kn, sb + 16384, tid); // T+1.AH
        MMCL(1, 1, bh);
    }

    float b2v[2][2];
#pragma unroll
    for (int qc = 0; qc < 2; qc++)
#pragma unroll
        for (int jj = 0; jj < 2; jj++)
            b2v[qc][jj] = (kz == 0) ? b2[e * DM + nt0 + qc * 128 + ac * 32 + jj * 16 + lm] : 0.f;

    float* Ye = Y + (size_t)kz * NSLOT * DM;
#pragma unroll
    for (int qr = 0; qr < 2; qr++)
#pragma unroll
        for (int ii = 0; ii < 4; ii++)
#pragma unroll
            for (int rr = 0; rr < 4; rr++) {
                int R = qr * 128 + ar * 64 + ii * 16 + q * 4 + rr;
                if (t0 + R < n_e) {   // GUARD: no cross-expert slot writes
                    float* yrow = Ye + (size_t)(slot0 + R) * DM + nt0;
#pragma unroll
                    for (int qc = 0; qc < 2; qc++)
#pragma unroll
                        for (int jj = 0; jj < 2; jj++)
                            yrow[qc * 128 + ac * 32 + jj * 16 + lm] = acc[qr][qc][ii][jj][rr] + b2v[qc][jj];
                }
            }
}

// ---------------- combine ----------------
__global__ __launch_bounds__(256)
void combine_kernel(const float* __restrict__ Y, const int* __restrict__ tslot,
                    const float* __restrict__ metaG, float4* __restrict__ out)
{
    const int t = blockIdx.x;
    const int c = threadIdx.x;
    int ts = tslot[t];
    int s0 = ts & 0xffff, s1 = (ts >> 16) & 0xffff;
    float g0 = metaG[t], g1 = 1.f - g0;
    const float4* Y0 = (const float4*)Y;
    const float4* Y1 = (const float4*)(Y + (size_t)NSLOT * DM);
    float4 a0 = Y0[(size_t)s0 * (DM / 4) + c];
    float4 a1 = Y1[(size_t)s0 * (DM / 4) + c];
    float4 c0 = Y0[(size_t)s1 * (DM / 4) + c];
    float4 c1 = Y1[(size_t)s1 * (DM / 4) + c];
    float4 o;
    o.x = g0 * (a0.x + a1.x) + g1 * (c0.x + c1.x);
    o.y = g0 * (a0.y + a1.y) + g1 * (c0.y + c1.y);
    o.z = g0 * (a0.z + a1.z) + g1 * (c0.z + c1.z);
    o.w = g0 * (a0.w + a1.w) + g1 * (c0.w + c1.w);
    out[(size_t)t * (DM / 4) + c] = o;
}

extern "C" void kernel_launch(void* const* d_in, const int* in_sizes, int n_in,
                              void* d_out, int out_size, void* d_ws, size_t ws_size,
                              hipStream_t stream)
{
    const float* x  = (const float*)d_in[0];
    const float* Wr = (const float*)d_in[1];
    const float* br = (const float*)d_in[2];
    const float* W1 = (const float*)d_in[3];
    const float* b1 = (const float*)d_in[4];
    const float* W2 = (const float*)d_in[5];
    const float* b2 = (const float*)d_in[6];
    float* out = (float*)d_out;

    char* ws = (char*)d_ws;
    int*    cnt   = (int*)(ws + CNT_OFF);
    int*    offs  = (int*)(ws + OFFS_OFF);
    int*    pos   = (int*)(ws + POS_OFF);
    int*    metaI = (int*)(ws + METAI_OFF);
    float*  metaG = (float*)(ws + METAG_OFF);
    int*    tslot = (int*)(ws + TSLOT_OFF);
    ushort* Xg    = (ushort*)(ws + XG_OFF);
    ushort* W1t   = (ushort*)(ws + W1T_OFF);
    ushort* H     = (ushort*)(ws + H_OFF);
    ushort* W2t   = (ushort*)(ws + W2T_OFF);
    float*  Y     = (float*)(ws + Y_OFF);     // aliases Xg+W1t (both dead after gemm1)

    init_kernel<<<1, 64, 0, stream>>>(cnt);
    wconv_kernel<<<dim3(DF / 64, DM / 64, NE), 256, 0, stream>>>(W1, W1t, DM, DF);
    wconv_kernel<<<dim3(DM / 64, DF / 64, NE), 256, 0, stream>>>(W2, W2t, DF, DM);
    router_kernel<<<TT / 4, 256, 0, stream>>>(x, Wr, br, cnt, metaI, metaG);
    scan_kernel<<<1, 64, 0, stream>>>(cnt, offs, pos);
    scatter_kernel<<<TT / 4, 256, 0, stream>>>(x, metaI, pos, tslot, Xg);

    gemm1_kernel<<<2048, 512, 0, stream>>>(Xg, W1t, b1, cnt, offs, H);
    gemm2_kernel<<<1024, 512, 0, stream>>>(H, W2t, b2, cnt, offs, Y);
    combine_kernel<<<TT, 256, 0, stream>>>(Y, tslot, metaG, (float4*)out);
}

// Round 5
// 586.997 us; speedup vs baseline: 1.2753x; 1.2237x over previous
//
#include <hip/hip_runtime.h>

#define TT 4096      // tokens
#define DM 1024      // d_model
#define DF 4096      // d_ff
#define NE 8         // experts
#define NSLOT 8192   // exactly 2*TT slots; M-overreach reads spill into adjacent ws (finite bf16, masked writes)

typedef short bf16x8 __attribute__((ext_vector_type(8)));
typedef float f32x4  __attribute__((ext_vector_type(4)));

// ---------- ws layout (bytes), total 218,234,880 (round-2 size, known OK) ----------
#define CNT_OFF    0
#define OFFS_OFF   256
#define METAI_OFF  4096                       // int[TT]
#define METAG_OFF  (METAI_OFF + 4*TT)         // float[TT]
#define TSLOT_OFF  (METAG_OFF + 4*TT)         // ushort[2*TT]: [2t]=s0, [2t+1]=s1 (int view = s0|s1<<16)
#define XG_OFF     131072                     // ushort[NSLOT*DM]   (dead after gemm1)
#define W1T_OFF    (XG_OFF + 2*NSLOT*DM)      // ushort[NE*DF*DM] bf16 [e][f][k] (dead after gemm1)
#define H_OFF      (W1T_OFF + 2*NE*DM*DF)     // ushort[NSLOT*DF]
#define W2T_OFF    (H_OFF + 2*NSLOT*DF)       // ushort[NE*DM*DF] bf16 [e][d][k]
#define Y_OFF      XG_OFF                     // float[2][NSLOT*DM] aliases Xg+W1t

// fp32 pair -> packed bf16x2 (RNE)
__device__ __forceinline__ unsigned pkbf(float a, float b) {
    unsigned ua = __float_as_uint(a), ub = __float_as_uint(b);
    ua += 0x7fffu + ((ua >> 16) & 1u);
    ub += 0x7fffu + ((ub >> 16) & 1u);
    return __builtin_amdgcn_perm(ub, ua, 0x07060302u);
}
// fp32 -> bf16 (RNE)
__device__ __forceinline__ ushort bf1(float x) {
    unsigned u = __float_as_uint(x);
    u += 0x7fffu + ((u >> 16) & 1u);
    return (ushort)(u >> 16);
}

// async global->LDS, 16B per lane; LDS dest linear (wave-uniform base + lane*16)
__device__ __forceinline__ void gll16(const void* g, void* l) {
    __builtin_amdgcn_global_load_lds(
        (const __attribute__((address_space(1))) void*)g,
        (__attribute__((address_space(3))) void*)l, 16, 0, 0);
}

// ---- BK=32 LDS tile layout (row-pair per 128B line), round-3-verified ----
// addr16(row,q) = (row>>1)*8 + phys, phys = (((row&1)<<2)|q) ^ ((row>>1)&7).
// Full-wave b128 frag reads: per 16-lane group every 16B bank-slot hit exactly
// twice (2-way = free, m136). Staged linear-dest + inverse-swizzled source.
__device__ __forceinline__ const bf16x8* fragp(const char* base, int row, int q) {
    int line = row >> 1;
    int c = ((((row & 1) << 2) | q) ^ (line & 7));
    return (const bf16x8*)(base + line * 128 + c * 16);
}

// stage one A(128x32, 8KB @0) + B(256x32, 16KB @8192) K32-tile; 3 gll16/thread (512 thr)
__device__ __forceinline__ void stage(const ushort* __restrict__ A, int ar0, int as,
                                      const ushort* __restrict__ B, int br0, int bs,
                                      int k0, char* buf, int tid)
{
    {   // A: 512 chunks
        int c = tid;
        int line = c >> 3, lg = (c & 7) ^ (line & 7);
        int row = line * 2 + (lg >> 2), kq = (lg & 3) * 8;
        gll16(A + (size_t)(ar0 + row) * as + k0 + kq, buf + c * 16);
    }
#pragma unroll
    for (int i = 0; i < 2; i++) {   // B: 1024 chunks
        int c = i * 512 + tid;
        int line = c >> 3, lg = (c & 7) ^ (line & 7);
        int row = line * 2 + (lg >> 2), kq = (lg & 3) * 8;
        gll16(B + (size_t)(br0 + row) * bs + k0 + kq, buf + 8192 + c * 16);
    }
}

// ---------------- Router: 1 wave/token, fp32 exact, NO atomics ----------------
__global__ __launch_bounds__(256)
void router_kernel(const float* __restrict__ x, const float* __restrict__ Wr,
                   const float* __restrict__ br,
                   int* __restrict__ meta_i, float* __restrict__ meta_g)
{
    const int t    = (blockIdx.x * blockDim.x + threadIdx.x) >> 6;
    const int lane = threadIdx.x & 63;
    if (t >= TT) return;
    const float* xr = x + (size_t)t * DM;

    float acc[NE];
#pragma unroll
    for (int e = 0; e < NE; e++) acc[e] = 0.f;
    for (int i = 0; i < DM / 64; i++) {
        int d = lane + (i << 6);
        float xv = xr[d];
        const float4* wr = (const float4*)(Wr + (size_t)d * NE);
        float4 w0 = wr[0], w1 = wr[1];
        acc[0] += xv * w0.x; acc[1] += xv * w0.y;
        acc[2] += xv * w0.z; acc[3] += xv * w0.w;
        acc[4] += xv * w1.x; acc[5] += xv * w1.y;
        acc[6] += xv * w1.z; acc[7] += xv * w1.w;
    }
#pragma unroll
    for (int e = 0; e < NE; e++)
#pragma unroll
        for (int off = 32; off > 0; off >>= 1)
            acc[e] += __shfl_down(acc[e], off, 64);

    if (lane == 0) {
        float lg[NE];
#pragma unroll
        for (int e = 0; e < NE; e++) lg[e] = acc[e] + br[e];
        int i0 = 0;
        for (int e = 1; e < NE; e++) if (lg[e] > lg[i0]) i0 = e;
        int i1 = (i0 == 0) ? 1 : 0;
        for (int e = 0; e < NE; e++) if (e != i0 && lg[e] > lg[i1]) i1 = e;
        float g0 = 1.f / (1.f + expf(lg[i1] - lg[i0]));  // renormalized top-2 softmax
        meta_i[t] = i0 | (i1 << 8);
        meta_g[t] = g0;
    }
}

// ------- slot assignment: 1 block, 8 waves (wave e owns expert e), ballot-rank -------
__global__ __launch_bounds__(512)
void slot_kernel(const int* __restrict__ metaI, int* __restrict__ cnt,
                 int* __restrict__ offs, ushort* __restrict__ tsl)
{
    __shared__ int sc[NE];
    const int lane = threadIdx.x & 63, e = threadIdx.x >> 6;
    const unsigned long long lt = (lane == 63) ? ~0ull >> 1 : ((1ull << lane) - 1);

    int total = 0;
    for (int c = 0; c < TT / 64; c++) {
        int mi = metaI[c * 64 + lane];
        bool hit = ((mi & 255) == e) || (((mi >> 8) & 255) == e);
        total += __popcll(__ballot(hit));
    }
    if (lane == 0) sc[e] = total;
    __syncthreads();
    int base = 0;
#pragma unroll
    for (int i = 0; i < NE; i++) base += (i < e) ? sc[i] : 0;
    if (threadIdx.x < NE) {
        cnt[threadIdx.x] = sc[threadIdx.x];
        int o = 0;
        for (int i = 0; i < (int)threadIdx.x; i++) o += sc[i];
        offs[threadIdx.x] = o;
    }
    for (int c = 0; c < TT / 64; c++) {
        int t = c * 64 + lane;
        int mi = metaI[t];
        bool h0 = ((mi & 255) == e);
        bool h1 = (((mi >> 8) & 255) == e);
        unsigned long long bal = __ballot(h0 || h1);
        int r = __popcll(bal & lt);
        if (h0) tsl[2 * t]     = (ushort)(base + r);
        if (h1) tsl[2 * t + 1] = (ushort)(base + r);
        base += __popcll(bal);
    }
}

// ---------------- scatter: gather x -> bf16 Xg (slots precomputed) ----------------
__global__ __launch_bounds__(256)
void scatter_kernel(const float* __restrict__ x, const ushort* __restrict__ tsl,
                    ushort* __restrict__ Xg)
{
    const int t    = (blockIdx.x * blockDim.x + threadIdx.x) >> 6;
    const int lane = threadIdx.x & 63;
    if (t >= TT) return;
    const int s0 = tsl[2 * t], s1 = tsl[2 * t + 1];
    const float4* xr = (const float4*)(x + (size_t)t * DM);
#pragma unroll
    for (int i = 0; i < 4; i++) {
        float4 v = xr[lane + 64 * i];
        uint2 pv = make_uint2(pkbf(v.x, v.y), pkbf(v.z, v.w));
        *(uint2*)(Xg + (size_t)s0 * DM + (lane + 64 * i) * 4) = pv;
        *(uint2*)(Xg + (size_t)s1 * DM + (lane + 64 * i) * 4) = pv;
    }
}

// ---------------- wconv: W[e][K][F] fp32 -> Wt[e][F][K] bf16 ----------------
__global__ __launch_bounds__(256)
void wconv_kernel(const float* __restrict__ W, ushort* __restrict__ Wt, int K, int F)
{
    const int e  = blockIdx.z;
    const int k0 = blockIdx.y * 64, f0 = blockIdx.x * 64;
    const float* We = W + (size_t)e * K * F;
    ushort* Oe = Wt + (size_t)e * K * F;

    __shared__ char lds[64 * 136];

    const int tid = threadIdx.x;
    const int a = tid & 15, b = tid >> 4;

    const float* src = We + (size_t)(k0 + b * 4) * F + f0 + a * 4;
    float4 v0 = *(const float4*)(src);
    float4 v1 = *(const float4*)(src + F);
    float4 v2 = *(const float4*)(src + 2 * F);
    float4 v3 = *(const float4*)(src + 3 * F);
    const float* p0 = (const float*)&v0; const float* p1 = (const float*)&v1;
    const float* p2 = (const float*)&v2; const float* p3 = (const float*)&v3;
#pragma unroll
    for (int j = 0; j < 4; j++) {
        int f = a * 4 + j;
        uint2 pv = make_uint2(pkbf(p0[j], p1[j]), pkbf(p2[j], p3[j]));
        *(uint2*)(lds + f * 136 + ((b ^ a) * 8)) = pv;
    }
    __syncthreads();
#pragma unroll
    for (int i = 0; i < 2; i++) {
        int idx = tid + 256 * i;
        int fl = idx >> 3, kc = idx & 7;
        int xw = fl >> 2;
        uint2 lo = *(const uint2*)(lds + fl * 136 + (((kc * 2)     ^ xw) * 8));
        uint2 hi = *(const uint2*)(lds + fl * 136 + (((kc * 2 + 1) ^ xw) * 8));
        uint4 o = make_uint4(lo.x, lo.y, hi.x, hi.y);
        *(uint4*)(Oe + (size_t)(f0 + fl) * K + k0 + kc * 8) = o;
    }
}

// ---------------- GEMM1: H = relu(Xg @ W1t^T + b1), 128x256 tile, 48KB LDS ----------------
__global__ __launch_bounds__(512)
void gemm1_kernel(const ushort* __restrict__ Xg, const ushort* __restrict__ W1t,
                  const float* __restrict__ b1, const int* __restrict__ cnt,
                  const int* __restrict__ offs, ushort* __restrict__ H)
{
    const int wg = blockIdx.x;            // e = wg&7 -> XCD-pinned expert
    const int e  = wg & 7;
    const int r  = wg >> 3;               // 0..255
    const int ft0 = (r & 15) * 256;
    const int t0  = (r >> 4) * 128;       // 16 tiles: covers n_e up to 2048
    const int n_e = cnt[e];
    if (t0 >= n_e) return;
    const int slot0 = offs[e] + t0;
    const ushort* Be = W1t + (size_t)e * DF * DM;   // [f][k]

    __shared__ char smem[49152];          // 2 x (A 8K | B 16K); epilogue Cb 64x264 bf16

    const int tid = threadIdx.x;
    const int l = tid & 63, wid = tid >> 6;
    const int wr = wid >> 2, wc = wid & 3;          // wave tile 64x64
    const int lm = l & 15, q = l >> 4;

    f32x4 acc[4][4];
#pragma unroll
    for (int i = 0; i < 4; i++)
#pragma unroll
        for (int j = 0; j < 4; j++) acc[i][j] = (f32x4){0.f, 0.f, 0.f, 0.f};

    stage(Xg, slot0, DM, Be, ft0, DM, 0, smem, tid);
    __syncthreads();

    const int NT = DM / 32;   // 32
    for (int kt = 0; kt < NT; ++kt) {
        char* cur = smem + (kt & 1) * 24576;
        if (kt + 1 < NT)
            stage(Xg, slot0, DM, Be, ft0, DM, (kt + 1) * 32,
                  smem + ((kt + 1) & 1) * 24576, tid);
        bf16x8 af[4], bfr[4];
#pragma unroll
        for (int i = 0; i < 4; i++) af[i] = *fragp(cur, wr * 64 + i * 16 + lm, q);
#pragma unroll
        for (int j = 0; j < 4; j++) bfr[j] = *fragp(cur + 8192, wc * 64 + j * 16 + lm, q);
#pragma unroll
        for (int i = 0; i < 4; i++)
#pragma unroll
            for (int j = 0; j < 4; j++)
                acc[i][j] = __builtin_amdgcn_mfma_f32_16x16x32_bf16(af[i], bfr[j], acc[i][j], 0, 0, 0);
        __syncthreads();
    }

    // epilogue: relu(+b1) -> bf16 H via LDS bounce, 2 stripes of 64 rows
    float b1v[4];
#pragma unroll
    for (int j = 0; j < 4; j++) b1v[j] = b1[e * DF + ft0 + wc * 64 + j * 16 + lm];

    ushort* Cb = (ushort*)smem;   // [64][264]
#pragma unroll
    for (int s = 0; s < 2; s++) {
        if (wr == s) {
#pragma unroll
            for (int i = 0; i < 4; i++)
#pragma unroll
                for (int j = 0; j < 4; j++)
#pragma unroll
                    for (int rr = 0; rr < 4; rr++) {
                        int lr  = i * 16 + q * 4 + rr;
                        int col = wc * 64 + j * 16 + lm;
                        Cb[lr * 264 + col] = bf1(fmaxf(acc[i][j][rr] + b1v[j], 0.f));
                    }
        }
        __syncthreads();
#pragma unroll
        for (int it = 0; it < 4; it++) {
            int idx = it * 512 + tid;
            int row = idx >> 5, ch = idx & 31;
            // GUARD: partial tiles must not write H rows of the next expert's slots
            if (t0 + s * 64 + row < n_e) {
                uint4 o = *(const uint4*)(Cb + row * 264 + ch * 8);
                *(uint4*)(H + (size_t)(slot0 + s * 64 + row) * DF + ft0 + ch * 8) = o;
            }
        }
        __syncthreads();
    }
}

// ---------------- GEMM2: Y[kz] = H @ W2t^T (+b2 on kz=0), 128x256 tile ----------------
__global__ __launch_bounds__(512)
void gemm2_kernel(const ushort* __restrict__ H, const ushort* __restrict__ W2t,
                  const float* __restrict__ b2, const int* __restrict__ cnt,
                  const int* __restrict__ offs, float* __restrict__ Y)
{
    const int wg = blockIdx.x;            // e = wg&7 -> XCD-pinned (both kz halves)
    const int e  = wg & 7;
    const int r  = wg >> 3;               // 0..127
    const int kz  = r & 1;
    const int nt0 = ((r >> 1) & 3) * 256;
    const int t0  = (r >> 3) * 128;       // 16 tiles
    const int n_e = cnt[e];
    if (t0 >= n_e) return;
    const int slot0 = offs[e] + t0;
    const ushort* Be = W2t + (size_t)e * DM * DF;   // [d][k]

    __shared__ char smem[49152];

    const int tid = threadIdx.x;
    const int l = tid & 63, wid = tid >> 6;
    const int wr = wid >> 2, wc = wid & 3;
    const int lm = l & 15, q = l >> 4;

    f32x4 acc[4][4];
#pragma unroll
    for (int i = 0; i < 4; i++)
#pragma unroll
        for (int j = 0; j < 4; j++) acc[i][j] = (f32x4){0.f, 0.f, 0.f, 0.f};

    const int kbeg = kz * (DF / 2);
    stage(H, slot0, DF, Be, nt0, DF, kbeg, smem, tid);
    __syncthreads();

    const int NT = (DF / 2) / 32;   // 64
    for (int kt = 0; kt < NT; ++kt) {
        char* cur = smem + (kt & 1) * 24576;
        if (kt + 1 < NT)
            stage(H, slot0, DF, Be, nt0, DF, kbeg + (kt + 1) * 32,
                  smem + ((kt + 1) & 1) * 24576, tid);
        bf16x8 af[4], bfr[4];
#pragma unroll
        for (int i = 0; i < 4; i++) af[i] = *fragp(cur, wr * 64 + i * 16 + lm, q);
#pragma unroll
        for (int j = 0; j < 4; j++) bfr[j] = *fragp(cur + 8192, wc * 64 + j * 16 + lm, q);
#pragma unroll
        for (int i = 0; i < 4; i++)
#pragma unroll
            for (int j = 0; j < 4; j++)
                acc[i][j] = __builtin_amdgcn_mfma_f32_16x16x32_bf16(af[i], bfr[j], acc[i][j], 0, 0, 0);
        __syncthreads();
    }

    float b2v[4];
#pragma unroll
    for (int j = 0; j < 4; j++)
        b2v[j] = (kz == 0) ? b2[e * DM + nt0 + wc * 64 + j * 16 + lm] : 0.f;

    float* Ye = Y + (size_t)kz * NSLOT * DM;
#pragma unroll
    for (int i = 0; i < 4; i++)
#pragma unroll
        for (int rr = 0; rr < 4; rr++) {
            int R = wr * 64 + i * 16 + q * 4 + rr;
            if (t0 + R < n_e) {   // GUARD: no cross-expert slot writes
                float* yrow = Ye + (size_t)(slot0 + R) * DM + nt0;
#pragma unroll
                for (int j = 0; j < 4; j++)
                    yrow[wc * 64 + j * 16 + lm] = acc[i][j][rr] + b2v[j];
            }
        }
}

// ---------------- combine: out[t] = g0*(Y0+Y1)[s0] + g1*(Y0+Y1)[s1] ----------------
__global__ __launch_bounds__(256)
void combine_kernel(const float* __restrict__ Y, const int* __restrict__ tslot,
                    const float* __restrict__ metaG, float4* __restrict__ out)
{
    const int t = blockIdx.x;
    const int c = threadIdx.x;
    int ts = tslot[t];
    int s0 = ts & 0xffff, s1 = (ts >> 16) & 0xffff;
    float g0 = metaG[t], g1 = 1.f - g0;
    const float4* Y0 = (const float4*)Y;
    const float4* Y1 = (const float4*)(Y + (size_t)NSLOT * DM);
    float4 a0 = Y0[(size_t)s0 * (DM / 4) + c];
    float4 a1 = Y1[(size_t)s0 * (DM / 4) + c];
    float4 c0 = Y0[(size_t)s1 * (DM / 4) + c];
    float4 c1 = Y1[(size_t)s1 * (DM / 4) + c];
    float4 o;
    o.x = g0 * (a0.x + a1.x) + g1 * (c0.x + c1.x);
    o.y = g0 * (a0.y + a1.y) + g1 * (c0.y + c1.y);
    o.z = g0 * (a0.z + a1.z) + g1 * (c0.z + c1.z);
    o.w = g0 * (a0.w + a1.w) + g1 * (c0.w + c1.w);
    out[(size_t)t * (DM / 4) + c] = o;
}

extern "C" void kernel_launch(void* const* d_in, const int* in_sizes, int n_in,
                              void* d_out, int out_size, void* d_ws, size_t ws_size,
                              hipStream_t stream)
{
    const float* x  = (const float*)d_in[0];
    const float* Wr = (const float*)d_in[1];
    const float* br = (const float*)d_in[2];
    const float* W1 = (const float*)d_in[3];
    const float* b1 = (const float*)d_in[4];
    const float* W2 = (const float*)d_in[5];
    const float* b2 = (const float*)d_in[6];
    float* out = (float*)d_out;

    char* ws = (char*)d_ws;
    int*    cnt   = (int*)(ws + CNT_OFF);
    int*    offs  = (int*)(ws + OFFS_OFF);
    int*    metaI = (int*)(ws + METAI_OFF);
    float*  metaG = (float*)(ws + METAG_OFF);
    ushort* tsl   = (ushort*)(ws + TSLOT_OFF);
    ushort* Xg    = (ushort*)(ws + XG_OFF);
    ushort* W1t   = (ushort*)(ws + W1T_OFF);
    ushort* H     = (ushort*)(ws + H_OFF);
    ushort* W2t   = (ushort*)(ws + W2T_OFF);
    float*  Y     = (float*)(ws + Y_OFF);     // aliases Xg+W1t (both dead after gemm1)

    wconv_kernel<<<dim3(DF / 64, DM / 64, NE), 256, 0, stream>>>(W1, W1t, DM, DF);
    wconv_kernel<<<dim3(DM / 64, DF / 64, NE), 256, 0, stream>>>(W2, W2t, DF, DM);
    router_kernel<<<TT / 4, 256, 0, stream>>>(x, Wr, br, metaI, metaG);
    slot_kernel<<<1, 512, 0, stream>>>(metaI, cnt, offs, tsl);
    scatter_kernel<<<TT / 4, 256, 0, stream>>>(x, tsl, Xg);

    gemm1_kernel<<<2048, 512, 0, stream>>>(Xg, W1t, b1, cnt, offs, H);
    gemm2_kernel<<<1024, 512, 0, stream>>>(H, W2t, b2, cnt, offs, Y);
    combine_kernel<<<TT, 256, 0, stream>>>(Y, (const int*)tsl, metaG, (float4*)out);
}